// Round 4
// baseline (211.917 us; speedup 1.0000x reference)
//
#include <hip/hip_runtime.h>
#include <hip/hip_bf16.h>
#include <stdint.h>

// ---------------------------------------------------------------------------
// Net_75282186764473 — forward == 'experiment' dynamics (stop_grad identity).
// Per step: sq = sin(1.1 q); q += dt*p_old; p += M'^T @ sq + dt*e
//   M' = dt*(c2q(W)+Qn-I) is SYMMETRIC -> use it as the MFMA A operand:
//   D[m=node][n=batch] += A[m=node][k] * B[k][n=batch],  k = prev node.
// A (M') lives in registers (pre-packed fragments, wave owns 3-4 node tiles);
// sin crosses waves via LDS [batch][k] bf16: C/D rows = 4 consecutive nodes
// -> one b64 write per tile; B-frag = b128 read of 8 consecutive k.
// Output = fac * q[:,196:206]  (65536 x 10 fp32).
// ---------------------------------------------------------------------------

typedef __attribute__((ext_vector_type(8))) short bh8;
typedef __attribute__((ext_vector_type(4))) float f32x4;

#define TILES 13        // node tiles of 16 -> 208 (>= 206)
#define KSTEPS 7        // k tiles of 32 -> 224 (A rows >= N are zero)
#define KSTR 232        // bf16 per LDS batch-row (464 B, 16B-aligned)
#define BB 16           // batch rows per block

static __device__ __forceinline__ uint16_t bf16_bits(float v) {
    __hip_bfloat16 h = __float2bfloat16(v);
    return *reinterpret_cast<uint16_t*>(&h);
}

// One prep kernel: per (stage,tile) block, compute the c2q diagonal for its
// 16 columns in-block, then pack A-frags of M' = dt*(c2q(C)+Qn-I):
// frag[((st*13+tile)*7+ks)*64+lane] = 8 bf16, elem j = M'[k][n],
//   k = ks*32+quad*8+j, n = tile*16+(lane&15).
__global__ void pack_frags(const float* __restrict__ C1, const float* __restrict__ Qn1,
                           const float* __restrict__ C2, const float* __restrict__ Qn2,
                           uint16_t* __restrict__ frag) {
    const int bid = blockIdx.x;                 // 0..25
    const int st = bid / TILES, tile = bid % TILES;
    const float* C  = st ? C2 : C1;
    const float* Qn = st ? Qn2 : Qn1;
    const int N = st ? 206 : 196;
    const int t = threadIdx.x;                  // 256
    __shared__ float part[256];
    __shared__ float dsh[16];
    // diag: 16 threads per column, strided partial sums
    {
        const int col = t & 15, seg = t >> 4;
        const int n0 = tile * 16 + col;
        float s = 0.f;
        if (n0 < N)
            for (int i = seg; i < N; i += 16)
                s += 0.5f * (C[i * N + n0] + C[n0 * N + i]);
        part[t] = s;
    }
    __syncthreads();
    if (t < 16) {
        float d = 0.f;
        #pragma unroll
        for (int j = 0; j < 16; ++j) d += part[j * 16 + t];
        dsh[t] = -d;
    }
    __syncthreads();
    const int lane = t & 63, grp = t >> 6;
    const int quad = (lane >> 4) & 3;
    const int n = tile * 16 + (lane & 15);
    for (int ks = grp; ks < KSTEPS; ks += 4) {
        uint16_t vals[8];
        #pragma unroll
        for (int j = 0; j < 8; ++j) {
            const int k = ks * 32 + quad * 8 + j;
            float v = 0.f;
            if (k < N && n < N) {
                if (k == n) v = dsh[lane & 15] + Qn[n * N + n] - 1.0f;
                else        v = 0.5f * (C[k * N + n] + C[n * N + k]) + Qn[k * N + n];
                v *= 0.1f;                      // fold dt
            }
            vals[j] = bf16_bits(v);
        }
        const size_t off = ((size_t)(st * TILES + tile) * KSTEPS + ks) * 64 + lane;
        reinterpret_cast<uint4*>(frag)[off] = *reinterpret_cast<uint4*>(vals);
    }
}

__global__ __launch_bounds__(256, 2) void pat_main(
    const float* __restrict__ x, const uint16_t* __restrict__ frag,
    const float* __restrict__ e1, const float* __restrict__ e2,
    const float* __restrict__ fac, float* __restrict__ out) {
    __shared__ __align__(16) uint16_t sinb[BB * KSTR];   // 7,424 B
    const int tid = threadIdx.x;
    const int lane = tid & 63;
    const int w = __builtin_amdgcn_readfirstlane(tid >> 6);   // 0..3
    const int c = lane & 15, quad = lane >> 4;
    const long batch = (long)blockIdx.x * BB + c;

    const int tiles[4] = {w, w + 4, w + 8, 12};
    const int ntiles = 3 + (w == 3);            // wave 3 also owns tile 12

    // zero the never-written k-pad rows 208..223 (A is zero there, but
    // 0 * LDS-garbage could be NaN)
    for (int z = tid; z < BB * (KSTR - 208); z += 256)
        sinb[(z / (KSTR - 208)) * KSTR + 208 + (z % (KSTR - 208))] = 0;

    const bh8* fragv = reinterpret_cast<const bh8*>(frag);
    bh8 A[4][KSTEPS];
    float q[4][4], er[4][4];
    f32x4 p[4];

    #pragma unroll
    for (int nt = 0; nt < 4; ++nt) {
        p[nt] = 0.f;
        if (nt < ntiles) {
            const int tile = tiles[nt];
            #pragma unroll
            for (int ks = 0; ks < KSTEPS; ++ks)
                A[nt][ks] = fragv[((size_t)tile * KSTEPS + ks) * 64 + lane];
            const int node0 = tile * 16 + quad * 4;
            if (node0 + 3 < 196) {
                const float4 v = *reinterpret_cast<const float4*>(x + batch * 196 + node0);
                q[nt][0] = v.x; q[nt][1] = v.y; q[nt][2] = v.z; q[nt][3] = v.w;
            } else {
                #pragma unroll
                for (int r = 0; r < 4; ++r)
                    q[nt][r] = (node0 + r < 196) ? x[batch * 196 + node0 + r] : 0.f;
            }
            #pragma unroll
            for (int r = 0; r < 4; ++r)
                er[nt][r] = (node0 + r < 196) ? 0.1f * e1[node0 + r] : 0.f;
        }
    }
    const float fout = fac[0];

    for (int st = 0; st < 10; ++st) {
        if (st == 5) {                          // stage switch: q carries, p resets
            #pragma unroll
            for (int nt = 0; nt < 4; ++nt)
                if (nt < ntiles) {
                    const int tile = tiles[nt];
                    #pragma unroll
                    for (int ks = 0; ks < KSTEPS; ++ks)
                        A[nt][ks] = fragv[((size_t)(TILES + tile) * KSTEPS + ks) * 64 + lane];
                    const int node0 = tile * 16 + quad * 4;
                    #pragma unroll
                    for (int r = 0; r < 4; ++r)
                        er[nt][r] = (node0 + r < 206) ? 0.1f * e2[node0 + r] : 0.f;
                    p[nt] = 0.f;
                }
        }
        // sin(q_old) -> LDS b64; q += dt*p_old
        #pragma unroll
        for (int nt = 0; nt < 4; ++nt)
            if (nt < ntiles) {
                const int tile = tiles[nt];
                uint2 u;
                u.x = (uint32_t)bf16_bits(__sinf(1.1f * q[nt][0]))
                    | ((uint32_t)bf16_bits(__sinf(1.1f * q[nt][1])) << 16);
                u.y = (uint32_t)bf16_bits(__sinf(1.1f * q[nt][2]))
                    | ((uint32_t)bf16_bits(__sinf(1.1f * q[nt][3])) << 16);
                *reinterpret_cast<uint2*>(&sinb[c * KSTR + tile * 16 + quad * 4]) = u;
                #pragma unroll
                for (int r = 0; r < 4; ++r) q[nt][r] += 0.1f * p[nt][r];
            }
        __syncthreads();
        // p += M' @ sin   (B-frag: batch row c, 8 consecutive k)
        #pragma unroll
        for (int ks = 0; ks < KSTEPS; ++ks) {
            const bh8 b = *reinterpret_cast<const bh8*>(&sinb[c * KSTR + ks * 32 + quad * 8]);
            #pragma unroll
            for (int nt = 0; nt < 4; ++nt)
                if (nt < ntiles)
                    p[nt] = __builtin_amdgcn_mfma_f32_16x16x32_bf16(A[nt][ks], b, p[nt], 0, 0, 0);
        }
        #pragma unroll
        for (int nt = 0; nt < 4; ++nt)
            if (nt < ntiles)
                #pragma unroll
                for (int r = 0; r < 4; ++r) p[nt][r] += er[nt][r];
        __syncthreads();
    }

    // outputs: nodes 196..205 live in tile 12 (wave 3, nt=3)
    if (w == 3) {
        const int node0 = 192 + quad * 4;
        #pragma unroll
        for (int r = 0; r < 4; ++r) {
            const int node = node0 + r;
            if (node >= 196 && node < 206)
                out[batch * 10 + (node - 196)] = fout * q[3][r];
        }
    }
}

extern "C" void kernel_launch(void* const* d_in, const int* in_sizes, int n_in,
                              void* d_out, int out_size, void* d_ws, size_t ws_size,
                              hipStream_t stream) {
    const float* x   = (const float*)d_in[0];
    const float* w1  = (const float*)d_in[1];
    const float* b1  = (const float*)d_in[2];
    const float* w2  = (const float*)d_in[3];
    const float* b2  = (const float*)d_in[4];
    const float* fac = (const float*)d_in[5];
    const float* qn1 = (const float*)d_in[6];
    const float* qn2 = (const float*)d_in[7];
    float* out = (float*)d_out;

    uint16_t* frg = (uint16_t*)d_ws;       // 2*13*7*64*16 B = 182 KB

    pack_frags<<<2 * TILES, 256, 0, stream>>>(w1, qn1, w2, qn2, frg);

    const int B = in_sizes[0] / 196;       // 65536
    pat_main<<<B / BB, 256, 0, stream>>>(x, frg, b1, b2, fac, out);
}

// Round 5
// 162.335 us; speedup vs baseline: 1.3054x; 1.3054x over previous
//
#include <hip/hip_runtime.h>
#include <hip/hip_bf16.h>
#include <stdint.h>

// ---------------------------------------------------------------------------
// Net_75282186764473 — forward == 'experiment' dynamics (stop_grad identity).
// Euler algebra: p0=0 -> q1=q0 -> D1=D0 -> p2=2*D0 (exact); last step's p is
// discarded. So per stage only 3 MFMA phases: D(q0), D(q2), D(q3), with
//   q2=q0+0.1*P ; P*=2 ; q3=q2+0.1*P ; [B] q4=q3+0.1*P ; [C] q5=q4+0.1*P.
// A = M'-fragments in registers (M' = dt*(c2q(W)+Qn-I), e folded as k=208 row
// driven by a constant 1.0 in the sin buffer). Sin crosses waves via 3 LDS
// buffers, pow2 row stride + XOR-block swizzle (2-way banks = free).
// 5 __syncthreads per block total. Output = fac * q[:,196:206].
// ---------------------------------------------------------------------------

typedef __attribute__((ext_vector_type(8))) short bh8;
typedef __attribute__((ext_vector_type(4))) float f32x4;

#define TILES 13        // node tiles of 16 -> 208 (>= 206)
#define KSTEPS 7        // k tiles of 32 -> 224 (k=208 is the e-row)
#define ROWDW 128       // dwords per LDS sin row (pow2; XOR swizzle on 16B blks)
#define BUFDW (16 * ROWDW)   // 2048 dwords per buffer

static __device__ __forceinline__ uint16_t bf16_bits(float v) {
    __hip_bfloat16 h = __float2bfloat16(v);
    return *reinterpret_cast<uint16_t*>(&h);
}

// Pack A-frags of M' = dt*(c2q(C)+Qn-I), plus e-row at k==208:
// frag[((st*13+tile)*7+ks)*64+lane] = 8 bf16, elem j = M'[k][n],
//   k = ks*32+quad*8+j, n = tile*16+(lane&15).
__global__ void pack_frags(const float* __restrict__ C1, const float* __restrict__ Qn1,
                           const float* __restrict__ e1,
                           const float* __restrict__ C2, const float* __restrict__ Qn2,
                           const float* __restrict__ e2,
                           uint16_t* __restrict__ frag) {
    const int bid = blockIdx.x;                 // 0..25
    const int st = bid / TILES, tile = bid % TILES;
    const float* C  = st ? C2 : C1;
    const float* Qn = st ? Qn2 : Qn1;
    const float* e  = st ? e2 : e1;
    const int N = st ? 206 : 196;
    const int t = threadIdx.x;                  // 256
    __shared__ float part[256];
    __shared__ float dsh[16];
    {   // c2q diagonal for this tile's 16 columns
        const int col = t & 15, seg = t >> 4;
        const int n0 = tile * 16 + col;
        float s = 0.f;
        if (n0 < N)
            for (int i = seg; i < N; i += 16)
                s += 0.5f * (C[i * N + n0] + C[n0 * N + i]);
        part[t] = s;
    }
    __syncthreads();
    if (t < 16) {
        float d = 0.f;
        #pragma unroll
        for (int j = 0; j < 16; ++j) d += part[j * 16 + t];
        dsh[t] = -d;
    }
    __syncthreads();
    const int lane = t & 63, grp = t >> 6;
    const int quad = (lane >> 4) & 3;
    const int n = tile * 16 + (lane & 15);
    for (int ks = grp; ks < KSTEPS; ks += 4) {
        uint16_t vals[8];
        #pragma unroll
        for (int j = 0; j < 8; ++j) {
            const int k = ks * 32 + quad * 8 + j;
            float v = 0.f;
            if (n < N) {
                if (k < N) {
                    if (k == n) v = dsh[lane & 15] + Qn[n * N + n] - 1.0f;
                    else        v = 0.5f * (C[k * N + n] + C[n * N + k]) + Qn[k * N + n];
                    v *= 0.1f;                  // fold dt
                } else if (k == 208) {
                    v = 0.1f * e[n];            // e-row (sin row 208 == 1.0)
                }
            }
            vals[j] = bf16_bits(v);
        }
        const size_t off = ((size_t)(st * TILES + tile) * KSTEPS + ks) * 64 + lane;
        reinterpret_cast<uint4*>(frag)[off] = *reinterpret_cast<uint4*>(vals);
    }
}

__global__ __launch_bounds__(256, 3) void pat_main(
    const float* __restrict__ x, const uint16_t* __restrict__ frag,
    const float* __restrict__ fac, float* __restrict__ out) {
    __shared__ __align__(16) uint32_t sinb[3 * BUFDW];    // 24,576 B
    const int tid = threadIdx.x;
    const int lane = tid & 63;
    const int w = __builtin_amdgcn_readfirstlane(tid >> 6);   // 0..3
    const int c = lane & 15, quad = lane >> 4;
    const uint32_t cs = (uint32_t)(c & 7);                    // XOR swizzle
    const long batch = (long)blockIdx.x * 16 + c;
    const int tiles[4] = {w, w + 4, w + 8, 12};
    const int ntiles = 3 + (w == 3);

    // zero all 3 buffers (pad rows 209..223 and swizzle spill blocks 28..31)
    {
        uint4 z; z.x = 0; z.y = 0; z.z = 0; z.w = 0;
        #pragma unroll
        for (int i = 0; i < 6; ++i)
            reinterpret_cast<uint4*>(sinb)[tid + i * 256] = z;
    }

    // A1 frags + x while the zero-fill settles
    const bh8* fragv = reinterpret_cast<const bh8*>(frag);
    bh8 A[4][KSTEPS];
    #pragma unroll
    for (int nt = 0; nt < 4; ++nt)
        if (nt < ntiles)
            #pragma unroll
            for (int ks = 0; ks < KSTEPS; ++ks)
                A[nt][ks] = fragv[((size_t)tiles[nt] * KSTEPS + ks) * 64 + lane];

    float q[4][4];
    f32x4 P[4];
    #pragma unroll
    for (int nt = 0; nt < 4; ++nt) {
        const int n0 = tiles[nt] * 16 + quad * 4;
        if (nt < ntiles) {
            if (n0 + 3 < 196) {
                const float4 v = *reinterpret_cast<const float4*>(x + batch * 196 + n0);
                q[nt][0] = v.x; q[nt][1] = v.y; q[nt][2] = v.z; q[nt][3] = v.w;
            } else {
                #pragma unroll
                for (int r = 0; r < 4; ++r)
                    q[nt][r] = (n0 + r < 196) ? x[batch * 196 + n0 + r] : 0.f;
            }
        } else {
            #pragma unroll
            for (int r = 0; r < 4; ++r) q[nt][r] = 0.f;
        }
        #pragma unroll
        for (int r = 0; r < 4; ++r) P[nt][r] = 0.f;
    }
    const float fout = fac[0];

    auto sin_phase = [&](int buf) {
        #pragma unroll
        for (int nt = 0; nt < 4; ++nt)
            if (nt < ntiles) {
                uint32_t d0 = (uint32_t)bf16_bits(__sinf(1.1f * q[nt][0]))
                            | ((uint32_t)bf16_bits(__sinf(1.1f * q[nt][1])) << 16);
                uint32_t d1 = (uint32_t)bf16_bits(__sinf(1.1f * q[nt][2]))
                            | ((uint32_t)bf16_bits(__sinf(1.1f * q[nt][3])) << 16);
                const uint32_t blk = ((uint32_t)(tiles[nt] * 2 + (quad >> 1))) ^ cs;
                uint2 u; u.x = d0; u.y = d1;
                *reinterpret_cast<uint2*>(
                    &sinb[buf * BUFDW + c * ROWDW + blk * 4 + (quad & 1) * 2]) = u;
            }
    };
    auto mfma_phase = [&](int buf) {
        #pragma unroll
        for (int ks = 0; ks < KSTEPS; ++ks) {
            const bh8 b = *reinterpret_cast<const bh8*>(
                &sinb[buf * BUFDW + c * ROWDW + (((uint32_t)(ks * 4 + quad)) ^ cs) * 4]);
            #pragma unroll
            for (int nt = 0; nt < 4; ++nt)
                if (nt < ntiles)
                    P[nt] = __builtin_amdgcn_mfma_f32_16x16x32_bf16(A[nt][ks], b, P[nt], 0, 0, 0);
        }
    };
    auto q_update = [&]() {
        #pragma unroll
        for (int nt = 0; nt < 4; ++nt)
            if (nt < ntiles)
                #pragma unroll
                for (int r = 0; r < 4; ++r)
                    q[nt][r] += 0.1f * P[nt][r];
    };

    __syncthreads();                       // zeros visible
    // constant 1.0 at sin row k=208 (e-drive), all 3 buffers
    if (tid < 48) {
        const int bb = tid >> 4, cc = tid & 15;
        sinb[bb * BUFDW + cc * ROWDW + (26u ^ (uint32_t)(cc & 7)) * 4] = 0x3F80u;
    }
    sin_phase(0);                          // sin(q0) -> bufA
    __syncthreads();

    for (int stg = 0; stg < 2; ++stg) {
        mfma_phase(0);                     // P = D0  (p1)
        q_update();                        // q2 = q0 + 0.1*D0   (q1 == q0)
        sin_phase(1);                      // sin(q2) -> bufB
        #pragma unroll
        for (int nt = 0; nt < 4; ++nt)
            #pragma unroll
            for (int r = 0; r < 4; ++r) P[nt][r] += P[nt][r];   // p2 = 2*D0
        q_update();                        // q3
        sin_phase(2);                      // sin(q3) -> bufC
        __syncthreads();
        mfma_phase(1);                     // p3
        q_update();                        // q4
        mfma_phase(2);                     // p4
        if (stg == 0) {                    // prefetch stage-2 A into freed regs
            #pragma unroll
            for (int nt = 0; nt < 4; ++nt)
                if (nt < ntiles)
                    #pragma unroll
                    for (int ks = 0; ks < KSTEPS; ++ks)
                        A[nt][ks] = fragv[((size_t)(TILES + tiles[nt]) * KSTEPS + ks) * 64 + lane];
        }
        q_update();                        // q5 (stage-final q)
        if (stg == 0) {
            #pragma unroll
            for (int nt = 0; nt < 4; ++nt)
                #pragma unroll
                for (int r = 0; r < 4; ++r) P[nt][r] = 0.f;     // p resets
            sin_phase(0);                  // sin(q5) -> bufA for stage 2
            __syncthreads();
        }
    }

    // outputs: nodes 196..205 live in tile 12 (wave 3, nt=3)
    if (w == 3) {
        const int n0 = 192 + quad * 4;
        #pragma unroll
        for (int r = 0; r < 4; ++r) {
            const int node = n0 + r;
            if (node >= 196 && node < 206)
                out[batch * 10 + (node - 196)] = fout * q[3][r];
        }
    }
}

extern "C" void kernel_launch(void* const* d_in, const int* in_sizes, int n_in,
                              void* d_out, int out_size, void* d_ws, size_t ws_size,
                              hipStream_t stream) {
    const float* x   = (const float*)d_in[0];
    const float* w1  = (const float*)d_in[1];
    const float* b1  = (const float*)d_in[2];
    const float* w2  = (const float*)d_in[3];
    const float* b2  = (const float*)d_in[4];
    const float* fac = (const float*)d_in[5];
    const float* qn1 = (const float*)d_in[6];
    const float* qn2 = (const float*)d_in[7];
    float* out = (float*)d_out;

    uint16_t* frg = (uint16_t*)d_ws;       // 2*13*7*64*16 B = 182 KB

    pack_frags<<<2 * TILES, 256, 0, stream>>>(w1, qn1, b1, w2, qn2, b2, frg);

    const int B = in_sizes[0] / 196;       // 65536
    pat_main<<<B / 16, 256, 0, stream>>>(x, frg, fac, out);
}